// Round 12
// baseline (353.456 us; speedup 1.0000x reference)
//
#include <hip/hip_runtime.h>
#include <hip/hip_bf16.h>
#include <stdint.h>

// Problem constants
#define M_B   1536      // 64*24 batch rows
#define N_L   500       // links
#define N_LP  512       // padded links (K of GEMM1, N of GEMM2)
#define N_P   20000     // paths
#define N_PP  20096     // padded paths (N of GEMM1 = 157*128, K of GEMM2)
#define N_G   4000      // OD groups
#define SPLITK 16
#define KCHUNK2 1280    // split-K chunk for GEMM2 (last = 896; both %32==0)
#define NQW   32        // row split for softmax (1-wave blocks)
#define GQW   (N_G / NQW)  // 125 groups per block
#define NCH   5         // static chunks: 5*256 = 1280 path capacity (~625 used)
#define SVC   1280      // LDS staged-value floats per block (+26 sigma margin)

// Workspace layout (bytes). Total ~228 MB. part aliases vp (vp dead after softmax).
#define OFF_A1   ((size_t)0)                    // bf16 [1536][512]      1,572,864
#define OFF_D1   ((size_t)1572864)              // bf16 [512][20096]    20,578,304
#define OFF_DT   ((size_t)22151168)             // bf16 [20096][512]    20,578,304
#define OFF_VP   ((size_t)42729472)             // f32  [1536][20096]  123,469,824
#define OFF_PART OFF_VP                         // f32  [16][1536][512] 50,331,648 (aliases vp)
#define OFF_F    ((size_t)166199296)            // bf16 [1536][20096]   61,734,912
#define OFF_BND  ((size_t)227934208)            // int  [4001]

typedef __bf16 bf16x8 __attribute__((ext_vector_type(8)));
typedef __bf16 bf16x4 __attribute__((ext_vector_type(4)));
typedef float  f32x4  __attribute__((ext_vector_type(4)));
typedef int    i32x4  __attribute__((ext_vector_type(4)));

__device__ __forceinline__ void gload16(const void* g, void* l) {
  __builtin_amdgcn_global_load_lds(
      (const __attribute__((address_space(1))) void*)g,
      (__attribute__((address_space(3))) void*)l, 16, 0, 0);
}

// monotonic float<->uint order-preserving mapping (for ds_max_u32-based float max)
__device__ __forceinline__ unsigned f2mono(float x) {
  unsigned u = __float_as_uint(x);
  return (u & 0x80000000u) ? ~u : (u | 0x80000000u);
}
__device__ __forceinline__ float mono2f(unsigned u) {
  u = (u & 0x80000000u) ? (u & 0x7fffffffu) : ~u;
  return __uint_as_float(u);
}

// ---- prep: v_links -> bf16 A1 [1536][512], zero-padded ----
__global__ __launch_bounds__(256) void prep_a1(const float* __restrict__ X,
                                               const float* __restrict__ theta,
                                               const float* __restrict__ theta_links,
                                               __bf16* __restrict__ A1) {
  int idx = blockIdx.x * 256 + threadIdx.x;           // over 1536*512
  if (idx >= M_B * N_LP) return;
  int b = idx >> 9, l = idx & (N_LP - 1);
  float v = 0.f;
  if (l < N_L) {
    const float* x = X + ((size_t)b * N_L + l) * 5;
#pragma unroll
    for (int f = 0; f < 5; ++f) v += x[f] * fminf(theta[f], 0.f);
    v += theta_links[l];
  }
  A1[idx] = (__bf16)v;
}

// ---- prep: D -> bf16 D1 [512][20096] (row copy) AND Dt [20096][512] (transpose) ----
__global__ __launch_bounds__(256) void prep_d(const float* __restrict__ D,
                                              __bf16* __restrict__ D1,
                                              __bf16* __restrict__ Dt) {
  __shared__ float t[32][33];
  int pb = blockIdx.x * 32;   // path block
  int lb = blockIdx.y * 32;   // link block
  for (int i = threadIdx.y; i < 32; i += 8) {
    int l = lb + i, p = pb + threadIdx.x;
    float v = (l < N_L && p < N_P) ? D[(size_t)l * N_P + p] : 0.f;
    t[i][threadIdx.x] = v;
    D1[(size_t)l * N_PP + p] = (__bf16)v;
  }
  __syncthreads();
  for (int i = threadIdx.y; i < 32; i += 8) {
    int p = pb + i, l = lb + threadIdx.x;
    Dt[(size_t)p * N_LP + l] = (__bf16)t[threadIdx.x][i];
  }
}

// ---- segment bounds: bounds[g] = first path index with seg >= g ----
__global__ __launch_bounds__(256) void seg_bounds(const int* __restrict__ seg,
                                                  int* __restrict__ bounds) {
  int g = blockIdx.x * 256 + threadIdx.x;
  if (g > N_G) return;
  int lo = 0, hi = N_P;
  while (lo < hi) { int mid = (lo + hi) >> 1; if (seg[mid] < g) lo = mid + 1; else hi = mid; }
  bounds[g] = lo;
}

// ---- GEMM (A and Bt row-major over K): C[m][n] = sum_k A[m][k]*Bt[n][k] ----
// 128x128 tile, 4 waves (2x2), BK=32 (m97 structure; BK=64 refuted R7/m132).
// ZSWZ=1: 1-D grid, z = bid&15 so XCD (= bid%8) pins z%8 -> D1 slices L2-resident.
template <int ZSWZ>
__global__ __launch_bounds__(256) void gemm_bt(const __bf16* __restrict__ A,
                                               const __bf16* __restrict__ Bt,
                                               float* __restrict__ C,
                                               int lda, int ldb, int ldc,
                                               int K, int kchunk, size_t zstride) {
  int bx, by, bz;
  if (ZSWZ) { int bid = blockIdx.x; bz = bid & 15; bx = (bid >> 4) & 3; by = bid >> 6; }
  else      { bx = blockIdx.x; by = blockIdx.y; bz = blockIdx.z; }
  __shared__ __bf16 lsA[128 * 32];
  __shared__ __bf16 lsB[128 * 32];
  const int tid = threadIdx.x;
  const int lane = tid & 63;
  const int wv = tid >> 6;
  const int wr = wv >> 1, wc = wv & 1;
  const int m0 = by * 128;
  const int n0 = bx * 128;
  const int kb = bz * kchunk;
  const int klen = min(kchunk, K - kb);

  const int srow = wv * 16 + (lane >> 2);
  const int scol = (lane & 3) * 8;
  const __bf16* gA = A + (size_t)(m0 + srow) * lda + kb + scol;
  const __bf16* gB = Bt + (size_t)(n0 + srow) * ldb + kb + scol;
  __bf16* lA0 = &lsA[(wv * 16) * 32];
  __bf16* lA1 = &lsA[(64 + wv * 16) * 32];
  __bf16* lB0 = &lsB[(wv * 16) * 32];
  __bf16* lB1 = &lsB[(64 + wv * 16) * 32];

  f32x4 acc[4][4] = {};
  const int fra = (wr * 64 + (lane & 15)) * 32 + 8 * (lane >> 4);
  const int frb = (wc * 64 + (lane & 15)) * 32 + 8 * (lane >> 4);

  for (int kk = 0; kk < klen; kk += 32) {
    gload16(gA + kk, lA0);
    gload16(gA + (size_t)64 * lda + kk, lA1);
    gload16(gB + kk, lB0);
    gload16(gB + (size_t)64 * ldb + kk, lB1);
    __syncthreads();
    bf16x8 av[4], bv[4];
#pragma unroll
    for (int r = 0; r < 4; ++r) av[r] = *(const bf16x8*)&lsA[fra + r * 16 * 32];
#pragma unroll
    for (int c = 0; c < 4; ++c) bv[c] = *(const bf16x8*)&lsB[frb + c * 16 * 32];
#pragma unroll
    for (int r = 0; r < 4; ++r)
#pragma unroll
      for (int c = 0; c < 4; ++c)
        acc[r][c] = __builtin_amdgcn_mfma_f32_16x16x32_bf16(av[r], bv[c], acc[r][c], 0, 0, 0);
    __syncthreads();
  }

  float* Cz = C + (size_t)bz * zstride;
  const int erow = m0 + wr * 64 + (lane >> 4) * 4;
  const int ecol = n0 + wc * 64 + (lane & 15);
#pragma unroll
  for (int r = 0; r < 4; ++r)
#pragma unroll
    for (int c = 0; c < 4; ++c) {
      float* p = Cz + (size_t)(erow + r * 16) * ldc + (ecol + c * 16);
#pragma unroll
      for (int j = 0; j < 4; ++j) p[(size_t)j * ldc] = acc[r][c][j];
    }
}

// ---- grouped softmax: 1-wave blocks, BRANCHLESS per-element LDS atomics. ----
// R5/R6/R10/R11 all ~96-101us regardless of traffic => divergent run-combine
// ladder was the cost (both exec-mask sides issue). Here: per element, clamp
// index + select identity value, one ds-atomic. v/e staged in LDS across passes
// (vp read once from L3). Lane stride = 4 paths ~ group size => same-address
// atomic collisions rare.
__global__ __launch_bounds__(64) void seg_softmax(const float* __restrict__ vp,
                                                  const int* __restrict__ bounds,
                                                  const int* __restrict__ seg,
                                                  const float* __restrict__ q_sqrt,
                                                  __bf16* __restrict__ f) {
  __shared__ float    sv[SVC];     // staged v (pass1) then e (pass2)
  __shared__ unsigned gmaxu[GQW];
  __shared__ float    den[GQW];    // denom, then scale q^2/denom
  const int tid = threadIdx.x;
  const int b = blockIdx.x;
  const int g0 = blockIdx.y * GQW;

  const unsigned NEGINF = f2mono(-3.4e38f);
  for (int i = tid; i < GQW; i += 64) { gmaxu[i] = NEGINF; den[i] = 0.f; }

  const int s0 = bounds[g0];
  const int e0 = (blockIdx.y == NQW - 1) ? N_P : bounds[g0 + GQW];
  const int s0a = s0 & ~3;
  const int e0a = (e0 + 3) & ~3;
  const float* row = vp + (size_t)b * N_PP;
  __syncthreads();   // init visible

  // pass 1: load vp -> LDS stage + branchless per-element atomicMax
#pragma unroll
  for (int c = 0; c < NCH; ++c) {
    int p = s0a + (c * 64 + tid) * 4;
    if (p >= e0a) continue;
    f32x4 v = *(const f32x4*)&row[p];
    i32x4 sgv = *(const i32x4*)&seg[p];
    *(f32x4*)&sv[p - s0a] = v;
#pragma unroll
    for (int j = 0; j < 4; ++j) {
      int gi = sgv[j] - g0;
      bool ok = (unsigned)gi < (unsigned)GQW;
      int idx = ok ? gi : 0;
      unsigned uv = ok ? f2mono(v[j]) : 0u;   // 0 < f2mono(-3.4e38): no-op on slot 0
      atomicMax(&gmaxu[idx], uv);
    }
  }
  __syncthreads();

  // pass 2: e = exp(v - gmax) (branchless), stage e, atomicAdd denom
#pragma unroll
  for (int c = 0; c < NCH; ++c) {
    int p = s0a + (c * 64 + tid) * 4;
    if (p >= e0a) continue;
    f32x4 v = *(const f32x4*)&sv[p - s0a];
    i32x4 sgv = *(const i32x4*)&seg[p];
    f32x4 e;
#pragma unroll
    for (int j = 0; j < 4; ++j) {
      int gi = sgv[j] - g0;
      bool ok = (unsigned)gi < (unsigned)GQW;
      int idx = ok ? gi : 0;
      float gm = mono2f(gmaxu[idx]);
      float ee = ok ? __expf(v[j] - gm) : 0.f;
      e[j] = ee;
      atomicAdd(&den[idx], ee);               // +0 on slot 0 when !ok
    }
    *(f32x4*)&sv[p - s0a] = e;
  }
  __syncthreads();

  // den -> scale = q^2 / den
  for (int g = tid; g < GQW; g += 64) {
    float d = den[g];
    if (d > 0.f) {
      float qs = q_sqrt[g0 + g];
      den[g] = qs * qs / d;
    }
  }
  __syncthreads();

  // pass 3: scale + store (vector when whole chunk in range)
  __bf16* frow = f + (size_t)b * N_PP;
#pragma unroll
  for (int c = 0; c < NCH; ++c) {
    int p = s0a + (c * 64 + tid) * 4;
    if (p >= e0a) continue;
    f32x4 e = *(const f32x4*)&sv[p - s0a];
    i32x4 sgv = *(const i32x4*)&seg[p];
    bf16x4 o;
    bool ok[4];
#pragma unroll
    for (int j = 0; j < 4; ++j) {
      int gi = sgv[j] - g0;
      ok[j] = (unsigned)gi < (unsigned)GQW;
      int idx = ok[j] ? gi : 0;
      o[j] = (__bf16)(e[j] * den[idx]);
    }
    if (ok[0] && ok[3]) {
      *(bf16x4*)&frow[p] = o;
    } else {
#pragma unroll
      for (int j = 0; j < 4; ++j)
        if (ok[j]) frow[p + j] = o[j];
    }
  }
  // zero padded tail so GEMM2's K-padding contributes nothing
  if (blockIdx.y == NQW - 1)
    for (int p = N_P + tid; p < N_PP; p += 64) frow[p] = (__bf16)0.f;
}

// ---- reduce split-K partials -> out (only l < 500) ----
__global__ __launch_bounds__(256) void reduce_out(const float* __restrict__ part,
                                                  float* __restrict__ out) {
  int idx = blockIdx.x * 256 + threadIdx.x;   // over 1536*500
  if (idx >= M_B * N_L) return;
  int b = idx / N_L, l = idx - b * N_L;
  float s = 0.f;
#pragma unroll
  for (int z = 0; z < SPLITK; ++z)
    s += part[(size_t)z * M_B * N_LP + (size_t)b * N_LP + l];
  out[idx] = s;
}

extern "C" void kernel_launch(void* const* d_in, const int* in_sizes, int n_in,
                              void* d_out, int out_size, void* d_ws, size_t ws_size,
                              hipStream_t stream) {
  const float* X           = (const float*)d_in[0];
  const float* theta       = (const float*)d_in[1];
  const float* theta_links = (const float*)d_in[2];
  const float* q_sqrt      = (const float*)d_in[3];
  const float* D           = (const float*)d_in[4];
  const int*   seg         = (const int*)d_in[5];
  float* out = (float*)d_out;

  char* ws = (char*)d_ws;
  __bf16* A1   = (__bf16*)(ws + OFF_A1);
  __bf16* D1   = (__bf16*)(ws + OFF_D1);
  __bf16* Dt   = (__bf16*)(ws + OFF_DT);
  float*  vp   = (float*)(ws + OFF_VP);
  float*  part = (float*)(ws + OFF_PART);
  __bf16* fbuf = (__bf16*)(ws + OFF_F);
  int*    bnd  = (int*)(ws + OFF_BND);

  prep_a1<<<(M_B * N_LP) / 256, 256, 0, stream>>>(X, theta, theta_links, A1);
  prep_d<<<dim3(N_PP / 32, N_LP / 32), dim3(32, 8), 0, stream>>>(D, D1, Dt);
  seg_bounds<<<16, 256, 0, stream>>>(seg, bnd);

  // GEMM1: vp[b][p] = sum_l A1[b][l] * Dt[p][l]
  gemm_bt<0><<<dim3(N_PP / 128, M_B / 128, 1), 256, 0, stream>>>(
      A1, Dt, vp, N_LP, N_LP, N_PP, N_LP, N_LP, (size_t)0);

  // softmax: 1-wave branchless blocks, grid (1536 rows, 32 group-slices)
  seg_softmax<<<dim3(M_B, NQW), 64, 0, stream>>>(vp, bnd, seg, q_sqrt, fbuf);

  // GEMM2 (split-K, z-swizzled 1-D grid): part[z][b][l] = sum_{k in z} f[b][k]*D1[l][k]
  gemm_bt<1><<<dim3((N_LP / 128) * (M_B / 128) * SPLITK, 1, 1), 256, 0, stream>>>(
      fbuf, D1, part, N_PP, N_PP, N_LP, N_PP, KCHUNK2, (size_t)(M_B * N_LP));

  reduce_out<<<(M_B * N_L + 255) / 256, 256, 0, stream>>>(part, out);
}

// Round 13
// 213.755 us; speedup vs baseline: 1.6536x; 1.6536x over previous
//
#include <hip/hip_runtime.h>
#include <hip/hip_bf16.h>
#include <stdint.h>

// Problem constants
#define M_B   1536      // 64*24 batch rows
#define N_L   500       // links
#define N_LP  512       // padded links (K of GEMM1, N of GEMM2)
#define N_P   20000     // paths
#define N_PP  20096     // padded paths (N of GEMM1 = 157*128, K of GEMM2)
#define N_G   4000      // OD groups
#define SPLITK 16
#define KCHUNK2 1280    // split-K chunk for GEMM2 (last = 896; both %32==0)
#define NQW   32        // row split for softmax (1-wave blocks)
#define GQW   (N_G / NQW)  // 125 groups per block
#define NCH   4         // sweep chunks: 4*256 = 1024 path capacity
#define SVC   1024      // LDS staged floats per block (slice ~625, sigma~25 -> +16 sigma)

// Workspace layout (bytes). Total ~228 MB. part aliases vp (vp dead after softmax).
#define OFF_A1   ((size_t)0)                    // bf16 [1536][512]      1,572,864
#define OFF_D1   ((size_t)1572864)              // bf16 [512][20096]    20,578,304
#define OFF_DT   ((size_t)22151168)             // bf16 [20096][512]    20,578,304
#define OFF_VP   ((size_t)42729472)             // f32  [1536][20096]  123,469,824
#define OFF_PART OFF_VP                         // f32  [16][1536][512] 50,331,648 (aliases vp)
#define OFF_F    ((size_t)166199296)            // bf16 [1536][20096]   61,734,912
#define OFF_BND  ((size_t)227934208)            // int  [4001]

typedef __bf16 bf16x8 __attribute__((ext_vector_type(8)));
typedef __bf16 bf16x4 __attribute__((ext_vector_type(4)));
typedef float  f32x4  __attribute__((ext_vector_type(4)));
typedef int    i32x4  __attribute__((ext_vector_type(4)));

__device__ __forceinline__ void gload16(const void* g, void* l) {
  __builtin_amdgcn_global_load_lds(
      (const __attribute__((address_space(1))) void*)g,
      (__attribute__((address_space(3))) void*)l, 16, 0, 0);
}

// ---- prep: v_links -> bf16 A1 [1536][512], zero-padded ----
__global__ __launch_bounds__(256) void prep_a1(const float* __restrict__ X,
                                               const float* __restrict__ theta,
                                               const float* __restrict__ theta_links,
                                               __bf16* __restrict__ A1) {
  int idx = blockIdx.x * 256 + threadIdx.x;           // over 1536*512
  if (idx >= M_B * N_LP) return;
  int b = idx >> 9, l = idx & (N_LP - 1);
  float v = 0.f;
  if (l < N_L) {
    const float* x = X + ((size_t)b * N_L + l) * 5;
#pragma unroll
    for (int f = 0; f < 5; ++f) v += x[f] * fminf(theta[f], 0.f);
    v += theta_links[l];
  }
  A1[idx] = (__bf16)v;
}

// ---- prep: D -> bf16 D1 [512][20096] (row copy) AND Dt [20096][512] (transpose) ----
__global__ __launch_bounds__(256) void prep_d(const float* __restrict__ D,
                                              __bf16* __restrict__ D1,
                                              __bf16* __restrict__ Dt) {
  __shared__ float t[32][33];
  int pb = blockIdx.x * 32;   // path block
  int lb = blockIdx.y * 32;   // link block
  for (int i = threadIdx.y; i < 32; i += 8) {
    int l = lb + i, p = pb + threadIdx.x;
    float v = (l < N_L && p < N_P) ? D[(size_t)l * N_P + p] : 0.f;
    t[i][threadIdx.x] = v;
    D1[(size_t)l * N_PP + p] = (__bf16)v;
  }
  __syncthreads();
  for (int i = threadIdx.y; i < 32; i += 8) {
    int p = pb + i, l = lb + threadIdx.x;
    Dt[(size_t)p * N_LP + l] = (__bf16)t[threadIdx.x][i];
  }
}

// ---- segment bounds: bounds[g] = first path index with seg >= g ----
__global__ __launch_bounds__(256) void seg_bounds(const int* __restrict__ seg,
                                                  int* __restrict__ bounds) {
  int g = blockIdx.x * 256 + threadIdx.x;
  if (g > N_G) return;
  int lo = 0, hi = N_P;
  while (lo < hi) { int mid = (lo + hi) >> 1; if (seg[mid] < g) lo = mid + 1; else hi = mid; }
  bounds[g] = lo;
}

// ---- GEMM (A and Bt row-major over K): C[m][n] = sum_k A[m][k]*Bt[n][k] ----
// 128x128 tile, 4 waves (2x2), BK=32 (m97 structure; BK=64 refuted R7/m132).
// ZSWZ=1: 1-D grid, z = bid&15 so XCD (= bid%8) pins z%8 -> D1 slices L2-resident.
template <int ZSWZ>
__global__ __launch_bounds__(256) void gemm_bt(const __bf16* __restrict__ A,
                                               const __bf16* __restrict__ Bt,
                                               float* __restrict__ C,
                                               int lda, int ldb, int ldc,
                                               int K, int kchunk, size_t zstride) {
  int bx, by, bz;
  if (ZSWZ) { int bid = blockIdx.x; bz = bid & 15; bx = (bid >> 4) & 3; by = bid >> 6; }
  else      { bx = blockIdx.x; by = blockIdx.y; bz = blockIdx.z; }
  __shared__ __bf16 lsA[128 * 32];
  __shared__ __bf16 lsB[128 * 32];
  const int tid = threadIdx.x;
  const int lane = tid & 63;
  const int wv = tid >> 6;
  const int wr = wv >> 1, wc = wv & 1;
  const int m0 = by * 128;
  const int n0 = bx * 128;
  const int kb = bz * kchunk;
  const int klen = min(kchunk, K - kb);

  const int srow = wv * 16 + (lane >> 2);
  const int scol = (lane & 3) * 8;
  const __bf16* gA = A + (size_t)(m0 + srow) * lda + kb + scol;
  const __bf16* gB = Bt + (size_t)(n0 + srow) * ldb + kb + scol;
  __bf16* lA0 = &lsA[(wv * 16) * 32];
  __bf16* lA1 = &lsA[(64 + wv * 16) * 32];
  __bf16* lB0 = &lsB[(wv * 16) * 32];
  __bf16* lB1 = &lsB[(64 + wv * 16) * 32];

  f32x4 acc[4][4] = {};
  const int fra = (wr * 64 + (lane & 15)) * 32 + 8 * (lane >> 4);
  const int frb = (wc * 64 + (lane & 15)) * 32 + 8 * (lane >> 4);

  for (int kk = 0; kk < klen; kk += 32) {
    gload16(gA + kk, lA0);
    gload16(gA + (size_t)64 * lda + kk, lA1);
    gload16(gB + kk, lB0);
    gload16(gB + (size_t)64 * ldb + kk, lB1);
    __syncthreads();
    bf16x8 av[4], bv[4];
#pragma unroll
    for (int r = 0; r < 4; ++r) av[r] = *(const bf16x8*)&lsA[fra + r * 16 * 32];
#pragma unroll
    for (int c = 0; c < 4; ++c) bv[c] = *(const bf16x8*)&lsB[frb + c * 16 * 32];
#pragma unroll
    for (int r = 0; r < 4; ++r)
#pragma unroll
      for (int c = 0; c < 4; ++c)
        acc[r][c] = __builtin_amdgcn_mfma_f32_16x16x32_bf16(av[r], bv[c], acc[r][c], 0, 0, 0);
    __syncthreads();
  }

  float* Cz = C + (size_t)bz * zstride;
  const int erow = m0 + wr * 64 + (lane >> 4) * 4;
  const int ecol = n0 + wc * 64 + (lane & 15);
#pragma unroll
  for (int r = 0; r < 4; ++r)
#pragma unroll
    for (int c = 0; c < 4; ++c) {
      float* p = Cz + (size_t)(erow + r * 16) * ldc + (ecol + c * 16);
#pragma unroll
      for (int j = 0; j < 4; ++j) p[(size_t)j * ldc] = acc[r][c][j];
    }
}

// ---- grouped softmax: 1-wave blocks, OWNER-LANE serial walks over LDS stage. ----
// R11/R12 showed the DS-atomic family floors at ~98us (atomic serialization).
// Here: zero atomics, zero shuffles. Stage slice (f32x4, coalesced) -> each lane
// owns group g0+round*64+lane (2 rounds), walks its ~5 contiguous elems in LDS:
// max walk, exp+sum walk (e written in place), ssc[g]=q^2/den. Then vectorized
// sweep: f32x4 LDS read + int4 seg + ssc lookup + bf16x4 coalesced store.
__global__ __launch_bounds__(64) void seg_softmax(const float* __restrict__ vp,
                                                  const int* __restrict__ bounds,
                                                  const int* __restrict__ seg,
                                                  const float* __restrict__ q_sqrt,
                                                  __bf16* __restrict__ f) {
  __shared__ float sv[SVC];      // staged v, overwritten with e by walks
  __shared__ float ssc[GQW];     // per-group scale q^2/den
  const int tid = threadIdx.x;
  const int b = blockIdx.x;
  const int g0 = blockIdx.y * GQW;

  const int s0 = bounds[g0];
  const int e0 = (blockIdx.y == NQW - 1) ? N_P : bounds[g0 + GQW];
  const int s0a = s0 & ~3;
  const int e0a = (e0 + 3) & ~3;
  const float* row = vp + (size_t)b * N_PP;

  // stage slice: coalesced f32x4
  for (int i = tid; i * 4 < e0a - s0a; i += 64)
    *(f32x4*)&sv[i * 4] = *(const f32x4*)&row[s0a + i * 4];
  __syncthreads();

  // owner-lane walks: 2 rounds of 64 groups
#pragma unroll
  for (int round = 0; round < 2; ++round) {
    int g = g0 + round * 64 + tid;
    if (g < g0 + GQW) {
      int s = bounds[g], e = bounds[g + 1];
      float m = -3.4e38f;
      for (int p = s; p < e; ++p) m = fmaxf(m, sv[p - s0a]);
      float den = 0.f;
      for (int p = s; p < e; ++p) {
        float t = __expf(sv[p - s0a] - m);
        den += t;
        sv[p - s0a] = t;
      }
      float qs = q_sqrt[g];
      ssc[g - g0] = (s < e) ? qs * qs / den : 0.f;
    }
  }
  __syncthreads();

  // vectorized sweep: scale + coalesced store (mask out-of-slice elems)
  __bf16* frow = f + (size_t)b * N_PP;
#pragma unroll
  for (int c = 0; c < NCH; ++c) {
    int p = s0a + (c * 64 + tid) * 4;
    if (p >= e0a) continue;
    f32x4 e4 = *(const f32x4*)&sv[p - s0a];
    i32x4 sgv = *(const i32x4*)&seg[p];
    bf16x4 o;
    bool ok[4];
#pragma unroll
    for (int j = 0; j < 4; ++j) {
      int gi = sgv[j] - g0;
      ok[j] = (unsigned)gi < (unsigned)GQW;
      int idx = ok[j] ? gi : 0;
      o[j] = (__bf16)(e4[j] * ssc[idx]);
    }
    if (ok[0] && ok[3]) {
      *(bf16x4*)&frow[p] = o;
    } else {
#pragma unroll
      for (int j = 0; j < 4; ++j)
        if (ok[j]) frow[p + j] = o[j];
    }
  }
  // zero padded tail so GEMM2's K-padding contributes nothing
  if (blockIdx.y == NQW - 1)
    for (int p = N_P + tid; p < N_PP; p += 64) frow[p] = (__bf16)0.f;
}

// ---- reduce split-K partials -> out (only l < 500) ----
__global__ __launch_bounds__(256) void reduce_out(const float* __restrict__ part,
                                                  float* __restrict__ out) {
  int idx = blockIdx.x * 256 + threadIdx.x;   // over 1536*500
  if (idx >= M_B * N_L) return;
  int b = idx / N_L, l = idx - b * N_L;
  float s = 0.f;
#pragma unroll
  for (int z = 0; z < SPLITK; ++z)
    s += part[(size_t)z * M_B * N_LP + (size_t)b * N_LP + l];
  out[idx] = s;
}

extern "C" void kernel_launch(void* const* d_in, const int* in_sizes, int n_in,
                              void* d_out, int out_size, void* d_ws, size_t ws_size,
                              hipStream_t stream) {
  const float* X           = (const float*)d_in[0];
  const float* theta       = (const float*)d_in[1];
  const float* theta_links = (const float*)d_in[2];
  const float* q_sqrt      = (const float*)d_in[3];
  const float* D           = (const float*)d_in[4];
  const int*   seg         = (const int*)d_in[5];
  float* out = (float*)d_out;

  char* ws = (char*)d_ws;
  __bf16* A1   = (__bf16*)(ws + OFF_A1);
  __bf16* D1   = (__bf16*)(ws + OFF_D1);
  __bf16* Dt   = (__bf16*)(ws + OFF_DT);
  float*  vp   = (float*)(ws + OFF_VP);
  float*  part = (float*)(ws + OFF_PART);
  __bf16* fbuf = (__bf16*)(ws + OFF_F);
  int*    bnd  = (int*)(ws + OFF_BND);

  prep_a1<<<(M_B * N_LP) / 256, 256, 0, stream>>>(X, theta, theta_links, A1);
  prep_d<<<dim3(N_PP / 32, N_LP / 32), dim3(32, 8), 0, stream>>>(D, D1, Dt);
  seg_bounds<<<16, 256, 0, stream>>>(seg, bnd);

  // GEMM1: vp[b][p] = sum_l A1[b][l] * Dt[p][l]
  gemm_bt<0><<<dim3(N_PP / 128, M_B / 128, 1), 256, 0, stream>>>(
      A1, Dt, vp, N_LP, N_LP, N_PP, N_LP, N_LP, (size_t)0);

  // softmax: 1-wave owner-lane blocks, grid (1536 rows, 32 group-slices)
  seg_softmax<<<dim3(M_B, NQW), 64, 0, stream>>>(vp, bnd, seg, q_sqrt, fbuf);

  // GEMM2 (split-K, z-swizzled 1-D grid): part[z][b][l] = sum_{k in z} f[b][k]*D1[l][k]
  gemm_bt<1><<<dim3((N_LP / 128) * (M_B / 128) * SPLITK, 1, 1), 256, 0, stream>>>(
      fbuf, D1, part, N_PP, N_PP, N_LP, N_PP, KCHUNK2, (size_t)(M_B * N_LP));

  reduce_out<<<(M_B * N_L + 255) / 256, 256, 0, stream>>>(part, out);
}

// Round 14
// 184.155 us; speedup vs baseline: 1.9193x; 1.1607x over previous
//
#include <hip/hip_runtime.h>
#include <hip/hip_bf16.h>
#include <stdint.h>

// Problem constants
#define M_B   1536      // 64*24 batch rows
#define N_L   500       // links
#define N_LP  512       // padded links (K of GEMM1, N of GEMM2)
#define N_P   20000     // paths
#define N_PP  20096     // padded paths (N of GEMM1 = 157*128, K of GEMM2)
#define N_G   4000      // OD groups
#define SPLITK 16
#define KCHUNK2 1280    // split-K chunk for GEMM2 (last = 896; both %32==0)
#define NQW   32        // row split for softmax (1-wave blocks)
#define GQW   (N_G / NQW)  // 125 groups per block
#define NCH   4         // sweep chunks: 4*256 = 1024 path capacity
#define SVC   1024      // LDS staged floats per block (slice ~625, sigma~25 -> +16 sigma)
#define NT1   (N_PP / 128)  // 157 n-tiles in GEMM1
#define MT1   (M_B / 128)   // 12 m-tiles
#define NB1   (NT1 * MT1)   // 1884 blocks

// Workspace layout (bytes). part aliases vp (vp dead after softmax).
#define OFF_A1   ((size_t)0)                    // bf16 [1536][512]      1,572,864
#define OFF_D1   ((size_t)1572864)              // bf16 [512][20096]    20,578,304
#define OFF_DT   ((size_t)22151168)             // bf16 [20096][512]    20,578,304
#define OFF_VP   ((size_t)42729472)             // bf16 [1536][20096]   61,734,912
#define OFF_PART OFF_VP                         // f32  [16][1536][512] 50,331,648 (aliases vp)
#define OFF_F    ((size_t)166199296)            // bf16 [1536][20096]   61,734,912
#define OFF_BND  ((size_t)227934208)            // int  [4001]

typedef __bf16 bf16x8 __attribute__((ext_vector_type(8)));
typedef __bf16 bf16x4 __attribute__((ext_vector_type(4)));
typedef float  f32x4  __attribute__((ext_vector_type(4)));
typedef int    i32x4  __attribute__((ext_vector_type(4)));

__device__ __forceinline__ void gload16(const void* g, void* l) {
  __builtin_amdgcn_global_load_lds(
      (const __attribute__((address_space(1))) void*)g,
      (__attribute__((address_space(3))) void*)l, 16, 0, 0);
}

// ---- prep: v_links -> bf16 A1 [1536][512], zero-padded ----
__global__ __launch_bounds__(256) void prep_a1(const float* __restrict__ X,
                                               const float* __restrict__ theta,
                                               const float* __restrict__ theta_links,
                                               __bf16* __restrict__ A1) {
  int idx = blockIdx.x * 256 + threadIdx.x;           // over 1536*512
  if (idx >= M_B * N_LP) return;
  int b = idx >> 9, l = idx & (N_LP - 1);
  float v = 0.f;
  if (l < N_L) {
    const float* x = X + ((size_t)b * N_L + l) * 5;
#pragma unroll
    for (int f = 0; f < 5; ++f) v += x[f] * fminf(theta[f], 0.f);
    v += theta_links[l];
  }
  A1[idx] = (__bf16)v;
}

// ---- prep: D -> bf16 D1 [512][20096] (row copy) AND Dt [20096][512] (transpose) ----
__global__ __launch_bounds__(256) void prep_d(const float* __restrict__ D,
                                              __bf16* __restrict__ D1,
                                              __bf16* __restrict__ Dt) {
  __shared__ float t[32][33];
  int pb = blockIdx.x * 32;   // path block
  int lb = blockIdx.y * 32;   // link block
  for (int i = threadIdx.y; i < 32; i += 8) {
    int l = lb + i, p = pb + threadIdx.x;
    float v = (l < N_L && p < N_P) ? D[(size_t)l * N_P + p] : 0.f;
    t[i][threadIdx.x] = v;
    D1[(size_t)l * N_PP + p] = (__bf16)v;
  }
  __syncthreads();
  for (int i = threadIdx.y; i < 32; i += 8) {
    int p = pb + i, l = lb + threadIdx.x;
    Dt[(size_t)p * N_LP + l] = (__bf16)t[threadIdx.x][i];
  }
}

// ---- segment bounds: bounds[g] = first path index with seg >= g ----
__global__ __launch_bounds__(256) void seg_bounds(const int* __restrict__ seg,
                                                  int* __restrict__ bounds) {
  int g = blockIdx.x * 256 + threadIdx.x;
  if (g > N_G) return;
  int lo = 0, hi = N_P;
  while (lo < hi) { int mid = (lo + hi) >> 1; if (seg[mid] < g) lo = mid + 1; else hi = mid; }
  bounds[g] = lo;
}

// ---- GEMM (A and Bt row-major over K): C[m][n] = sum_k A[m][k]*Bt[n][k] ----
// 128x128 tile, 4 waves (2x2), BK=32 (m97 structure; BK=64 refuted R7/m132).
// MODE=1 (GEMM1): 1-D grid NB1, bijective XCD-chunked n-major map — XCD x
//   (= bid&7 dispatch heuristic) owns a contiguous L-range; its ~20 Dt n-tiles
//   (2.5 MB) stay L2-resident. B_x=236 (x<4) else 235; L=start_x + (bid>>3).
// MODE=2 (GEMM2): z-major z=bid&15 -> 2 K-chunks per XCD, D1 slices L2-resident.
// OBF=1: store C as bf16 (halves vp write traffic).
template <int MODE, int OBF>
__global__ __launch_bounds__(256) void gemm_bt(const __bf16* __restrict__ A,
                                               const __bf16* __restrict__ Bt,
                                               void* __restrict__ C,
                                               int lda, int ldb, int ldc,
                                               int K, int kchunk, size_t zstride) {
  int bx, by, bz;
  if (MODE == 1) {
    int x = blockIdx.x & 7, k = blockIdx.x >> 3;
    int start = (x < 4) ? 236 * x : 944 + 235 * (x - 4);
    int L = start + k;
    bx = L / MT1;  by = L - bx * MT1;  bz = 0;
  } else {
    int bid = blockIdx.x; bz = bid & 15; bx = (bid >> 4) & 3; by = bid >> 6;
  }
  __shared__ __bf16 lsA[128 * 32];
  __shared__ __bf16 lsB[128 * 32];
  const int tid = threadIdx.x;
  const int lane = tid & 63;
  const int wv = tid >> 6;
  const int wr = wv >> 1, wc = wv & 1;
  const int m0 = by * 128;
  const int n0 = bx * 128;
  const int kb = bz * kchunk;
  const int klen = min(kchunk, K - kb);

  const int srow = wv * 16 + (lane >> 2);
  const int scol = (lane & 3) * 8;
  const __bf16* gA = A + (size_t)(m0 + srow) * lda + kb + scol;
  const __bf16* gB = Bt + (size_t)(n0 + srow) * ldb + kb + scol;
  __bf16* lA0 = &lsA[(wv * 16) * 32];
  __bf16* lA1 = &lsA[(64 + wv * 16) * 32];
  __bf16* lB0 = &lsB[(wv * 16) * 32];
  __bf16* lB1 = &lsB[(64 + wv * 16) * 32];

  f32x4 acc[4][4] = {};
  const int fra = (wr * 64 + (lane & 15)) * 32 + 8 * (lane >> 4);
  const int frb = (wc * 64 + (lane & 15)) * 32 + 8 * (lane >> 4);

  for (int kk = 0; kk < klen; kk += 32) {
    gload16(gA + kk, lA0);
    gload16(gA + (size_t)64 * lda + kk, lA1);
    gload16(gB + kk, lB0);
    gload16(gB + (size_t)64 * ldb + kk, lB1);
    __syncthreads();
    bf16x8 av[4], bv[4];
#pragma unroll
    for (int r = 0; r < 4; ++r) av[r] = *(const bf16x8*)&lsA[fra + r * 16 * 32];
#pragma unroll
    for (int c = 0; c < 4; ++c) bv[c] = *(const bf16x8*)&lsB[frb + c * 16 * 32];
#pragma unroll
    for (int r = 0; r < 4; ++r)
#pragma unroll
      for (int c = 0; c < 4; ++c)
        acc[r][c] = __builtin_amdgcn_mfma_f32_16x16x32_bf16(av[r], bv[c], acc[r][c], 0, 0, 0);
    __syncthreads();
  }

  const int erow = m0 + wr * 64 + (lane >> 4) * 4;
  const int ecol = n0 + wc * 64 + (lane & 15);
#pragma unroll
  for (int r = 0; r < 4; ++r)
#pragma unroll
    for (int c = 0; c < 4; ++c) {
      if (OBF) {
        __bf16* p = (__bf16*)C + (size_t)(erow + r * 16) * ldc + (ecol + c * 16);
#pragma unroll
        for (int j = 0; j < 4; ++j) p[(size_t)j * ldc] = (__bf16)acc[r][c][j];
      } else {
        float* p = (float*)C + (size_t)bz * zstride +
                   (size_t)(erow + r * 16) * ldc + (ecol + c * 16);
#pragma unroll
        for (int j = 0; j < 4; ++j) p[(size_t)j * ldc] = acc[r][c][j];
      }
    }
}

// ---- grouped softmax: 1-wave blocks, owner-lane serial walks over LDS stage. ----
// (R13 structure — best measured.) vp now bf16: stage converts bf16->f32 in LDS;
// walks and exp stay f32. Zero atomics, zero shuffles.
__global__ __launch_bounds__(64) void seg_softmax(const __bf16* __restrict__ vp,
                                                  const int* __restrict__ bounds,
                                                  const int* __restrict__ seg,
                                                  const float* __restrict__ q_sqrt,
                                                  __bf16* __restrict__ f) {
  __shared__ float sv[SVC];      // staged v (f32), overwritten with e by walks
  __shared__ float ssc[GQW];     // per-group scale q^2/den
  const int tid = threadIdx.x;
  const int b = blockIdx.x;
  const int g0 = blockIdx.y * GQW;

  const int s0 = bounds[g0];
  const int e0 = (blockIdx.y == NQW - 1) ? N_P : bounds[g0 + GQW];
  const int s0a = s0 & ~3;
  const int e0a = (e0 + 3) & ~3;
  const __bf16* row = vp + (size_t)b * N_PP;

  // stage slice: coalesced bf16x4 load, convert to f32
  for (int i = tid; i * 4 < e0a - s0a; i += 64) {
    bf16x4 v4 = *(const bf16x4*)&row[s0a + i * 4];
    f32x4 v;
#pragma unroll
    for (int j = 0; j < 4; ++j) v[j] = (float)v4[j];
    *(f32x4*)&sv[i * 4] = v;
  }
  __syncthreads();

  // owner-lane walks: 2 rounds of 64 groups
#pragma unroll
  for (int round = 0; round < 2; ++round) {
    int g = g0 + round * 64 + tid;
    if (g < g0 + GQW) {
      int s = bounds[g], e = bounds[g + 1];
      float m = -3.4e38f;
      for (int p = s; p < e; ++p) m = fmaxf(m, sv[p - s0a]);
      float den = 0.f;
      for (int p = s; p < e; ++p) {
        float t = __expf(sv[p - s0a] - m);
        den += t;
        sv[p - s0a] = t;
      }
      float qs = q_sqrt[g];
      ssc[g - g0] = (s < e) ? qs * qs / den : 0.f;
    }
  }
  __syncthreads();

  // vectorized sweep: scale + coalesced store (mask out-of-slice elems)
  __bf16* frow = f + (size_t)b * N_PP;
#pragma unroll
  for (int c = 0; c < NCH; ++c) {
    int p = s0a + (c * 64 + tid) * 4;
    if (p >= e0a) continue;
    f32x4 e4 = *(const f32x4*)&sv[p - s0a];
    i32x4 sgv = *(const i32x4*)&seg[p];
    bf16x4 o;
    bool ok[4];
#pragma unroll
    for (int j = 0; j < 4; ++j) {
      int gi = sgv[j] - g0;
      ok[j] = (unsigned)gi < (unsigned)GQW;
      int idx = ok[j] ? gi : 0;
      o[j] = (__bf16)(e4[j] * ssc[idx]);
    }
    if (ok[0] && ok[3]) {
      *(bf16x4*)&frow[p] = o;
    } else {
#pragma unroll
      for (int j = 0; j < 4; ++j)
        if (ok[j]) frow[p + j] = o[j];
    }
  }
  // zero padded tail so GEMM2's K-padding contributes nothing
  if (blockIdx.y == NQW - 1)
    for (int p = N_P + tid; p < N_PP; p += 64) frow[p] = (__bf16)0.f;
}

// ---- reduce split-K partials -> out (only l < 500) ----
__global__ __launch_bounds__(256) void reduce_out(const float* __restrict__ part,
                                                  float* __restrict__ out) {
  int idx = blockIdx.x * 256 + threadIdx.x;   // over 1536*500
  if (idx >= M_B * N_L) return;
  int b = idx / N_L, l = idx - b * N_L;
  float s = 0.f;
#pragma unroll
  for (int z = 0; z < SPLITK; ++z)
    s += part[(size_t)z * M_B * N_LP + (size_t)b * N_LP + l];
  out[idx] = s;
}

extern "C" void kernel_launch(void* const* d_in, const int* in_sizes, int n_in,
                              void* d_out, int out_size, void* d_ws, size_t ws_size,
                              hipStream_t stream) {
  const float* X           = (const float*)d_in[0];
  const float* theta       = (const float*)d_in[1];
  const float* theta_links = (const float*)d_in[2];
  const float* q_sqrt      = (const float*)d_in[3];
  const float* D           = (const float*)d_in[4];
  const int*   seg         = (const int*)d_in[5];
  float* out = (float*)d_out;

  char* ws = (char*)d_ws;
  __bf16* A1   = (__bf16*)(ws + OFF_A1);
  __bf16* D1   = (__bf16*)(ws + OFF_D1);
  __bf16* Dt   = (__bf16*)(ws + OFF_DT);
  __bf16* vp   = (__bf16*)(ws + OFF_VP);
  float*  part = (float*)(ws + OFF_PART);
  __bf16* fbuf = (__bf16*)(ws + OFF_F);
  int*    bnd  = (int*)(ws + OFF_BND);

  prep_a1<<<(M_B * N_LP) / 256, 256, 0, stream>>>(X, theta, theta_links, A1);
  prep_d<<<dim3(N_PP / 32, N_LP / 32), dim3(32, 8), 0, stream>>>(D, D1, Dt);
  seg_bounds<<<16, 256, 0, stream>>>(seg, bnd);

  // GEMM1 (XCD-chunked, bf16 out): vp[b][p] = sum_l A1[b][l] * Dt[p][l]
  gemm_bt<1, 1><<<dim3(NB1, 1, 1), 256, 0, stream>>>(
      A1, Dt, vp, N_LP, N_LP, N_PP, N_LP, N_LP, (size_t)0);

  // softmax: 1-wave owner-lane blocks, grid (1536 rows, 32 group-slices)
  seg_softmax<<<dim3(M_B, NQW), 64, 0, stream>>>(vp, bnd, seg, q_sqrt, fbuf);

  // GEMM2 (split-K, z-swizzled): part[z][b][l] = sum_{k in z} f[b][k]*D1[l][k]
  gemm_bt<2, 0><<<dim3((N_LP / 128) * (M_B / 128) * SPLITK, 1, 1), 256, 0, stream>>>(
      fbuf, D1, part, N_PP, N_PP, N_LP, N_PP, KCHUNK2, (size_t)(M_B * N_LP));

  reduce_out<<<(M_B * N_L + 255) / 256, 256, 0, stream>>>(part, out);
}

// Round 15
// 177.564 us; speedup vs baseline: 1.9906x; 1.0371x over previous
//
#include <hip/hip_runtime.h>
#include <hip/hip_bf16.h>
#include <stdint.h>

// Problem constants
#define M_B   1536      // 64*24 batch rows
#define N_L   500       // links
#define N_LP  512       // padded links (K of GEMM1, N of GEMM2)
#define N_P   20000     // paths
#define N_PP  20096     // padded paths (N of GEMM1 = 157*128, K of GEMM2)
#define N_G   4000      // OD groups
#define SPLITK 16
#define KCHUNK2 1280    // split-K chunk for GEMM2 (last = 896; both %32==0)
#define NQW   32        // row split for softmax (1-wave blocks)
#define GQW   (N_G / NQW)  // 125 groups per block
#define NCH   4         // sweep chunks: 4*256 = 1024 path capacity
#define SVC   1024      // LDS staged floats per block (slice ~625, sigma~25 -> +16 sigma)
#define NT1   (N_PP / 128)  // 157 n-tiles in GEMM1
#define MT1   (M_B / 128)   // 12 m-tiles
#define NB1   (NT1 * MT1)   // 1884 blocks

// Workspace layout (bytes). part aliases vp (vp dead after softmax).
#define OFF_A1   ((size_t)0)                    // bf16 [1536][512]      1,572,864
#define OFF_D1   ((size_t)1572864)              // bf16 [512][20096]    20,578,304
#define OFF_DT   ((size_t)22151168)             // bf16 [20096][512]    20,578,304
#define OFF_VP   ((size_t)42729472)             // bf16 [1536][20096]   61,734,912
#define OFF_PART OFF_VP                         // f32  [16][1536][512] 50,331,648 (aliases vp)
#define OFF_F    ((size_t)166199296)            // bf16 [1536][20096]   61,734,912
#define OFF_BND  ((size_t)227934208)            // int  [4001]

typedef __bf16 bf16x8 __attribute__((ext_vector_type(8)));
typedef __bf16 bf16x4 __attribute__((ext_vector_type(4)));
typedef float  f32x4  __attribute__((ext_vector_type(4)));
typedef int    i32x4  __attribute__((ext_vector_type(4)));

__device__ __forceinline__ void gload16(const void* g, void* l) {
  __builtin_amdgcn_global_load_lds(
      (const __attribute__((address_space(1))) void*)g,
      (__attribute__((address_space(3))) void*)l, 16, 0, 0);
}

// ---- prep: v_links -> bf16 A1 [1536][512], zero-padded ----
__global__ __launch_bounds__(256) void prep_a1(const float* __restrict__ X,
                                               const float* __restrict__ theta,
                                               const float* __restrict__ theta_links,
                                               __bf16* __restrict__ A1) {
  int idx = blockIdx.x * 256 + threadIdx.x;           // over 1536*512
  if (idx >= M_B * N_LP) return;
  int b = idx >> 9, l = idx & (N_LP - 1);
  float v = 0.f;
  if (l < N_L) {
    const float* x = X + ((size_t)b * N_L + l) * 5;
#pragma unroll
    for (int f = 0; f < 5; ++f) v += x[f] * fminf(theta[f], 0.f);
    v += theta_links[l];
  }
  A1[idx] = (__bf16)v;
}

// ---- prep: D -> bf16 D1 [512][20096] (row copy) AND Dt [20096][512] (transpose) ----
__global__ __launch_bounds__(256) void prep_d(const float* __restrict__ D,
                                              __bf16* __restrict__ D1,
                                              __bf16* __restrict__ Dt) {
  __shared__ float t[32][33];
  int pb = blockIdx.x * 32;   // path block
  int lb = blockIdx.y * 32;   // link block
  for (int i = threadIdx.y; i < 32; i += 8) {
    int l = lb + i, p = pb + threadIdx.x;
    float v = (l < N_L && p < N_P) ? D[(size_t)l * N_P + p] : 0.f;
    t[i][threadIdx.x] = v;
    D1[(size_t)l * N_PP + p] = (__bf16)v;
  }
  __syncthreads();
  for (int i = threadIdx.y; i < 32; i += 8) {
    int p = pb + i, l = lb + threadIdx.x;
    Dt[(size_t)p * N_LP + l] = (__bf16)t[threadIdx.x][i];
  }
}

// ---- segment bounds: bounds[g] = first path index with seg >= g ----
__global__ __launch_bounds__(256) void seg_bounds(const int* __restrict__ seg,
                                                  int* __restrict__ bounds) {
  int g = blockIdx.x * 256 + threadIdx.x;
  if (g > N_G) return;
  int lo = 0, hi = N_P;
  while (lo < hi) { int mid = (lo + hi) >> 1; if (seg[mid] < g) lo = mid + 1; else hi = mid; }
  bounds[g] = lo;
}

// ---- GEMM (A and Bt row-major over K): C[m][n] = sum_k A[m][k]*Bt[n][k] ----
// 128x128 tile, 4 waves (2x2), BK=32, T3+T4 minimum 2-PHASE: double-buffered LDS,
// next tile's global_load_lds issued BEFORE current tile's ds_read+MFMA, single
// vmcnt(0)+barrier per tile (in __syncthreads). R14 structure exposed the full
// load latency every iteration (stage -> drain -> compute); m233: that drain is
// the dominant stall of the 2-barrier loop.
// MODE=1 (GEMM1): bijective XCD-chunked n-major map (Dt tiles L2-resident/XCD).
// MODE=2 (GEMM2): z-major z=bid&15 (D1 slices L2-resident/XCD).
// OBF=1: store C as bf16 (halves vp write traffic).
template <int MODE, int OBF>
__global__ __launch_bounds__(256) void gemm_bt(const __bf16* __restrict__ A,
                                               const __bf16* __restrict__ Bt,
                                               void* __restrict__ C,
                                               int lda, int ldb, int ldc,
                                               int K, int kchunk, size_t zstride) {
  int bx, by, bz;
  if (MODE == 1) {
    int x = blockIdx.x & 7, k = blockIdx.x >> 3;
    int start = (x < 4) ? 236 * x : 944 + 235 * (x - 4);
    int L = start + k;
    bx = L / MT1;  by = L - bx * MT1;  bz = 0;
  } else {
    int bid = blockIdx.x; bz = bid & 15; bx = (bid >> 4) & 3; by = bid >> 6;
  }
  __shared__ __bf16 lsA[2][128 * 32];
  __shared__ __bf16 lsB[2][128 * 32];
  const int tid = threadIdx.x;
  const int lane = tid & 63;
  const int wv = tid >> 6;
  const int wr = wv >> 1, wc = wv & 1;
  const int m0 = by * 128;
  const int n0 = bx * 128;
  const int kb = bz * kchunk;
  const int klen = min(kchunk, K - kb);

  const int srow = wv * 16 + (lane >> 2);
  const int scol = (lane & 3) * 8;
  const int sb = (wv * 16) * 32;            // wave's staging base within a buffer
  const __bf16* gA = A + (size_t)(m0 + srow) * lda + kb + scol;
  const __bf16* gB = Bt + (size_t)(n0 + srow) * ldb + kb + scol;

  f32x4 acc[4][4] = {};
  const int fra = (wr * 64 + (lane & 15)) * 32 + 8 * (lane >> 4);
  const int frb = (wc * 64 + (lane & 15)) * 32 + 8 * (lane >> 4);

#define STAGE(buf, kk)                                                        \
  {                                                                           \
    gload16(gA + (kk), &lsA[buf][sb]);                                        \
    gload16(gA + (size_t)64 * lda + (kk), &lsA[buf][64 * 32 + sb]);           \
    gload16(gB + (kk), &lsB[buf][sb]);                                        \
    gload16(gB + (size_t)64 * ldb + (kk), &lsB[buf][64 * 32 + sb]);           \
  }
#define COMPUTE(buf)                                                          \
  {                                                                           \
    bf16x8 av[4], bv[4];                                                      \
    _Pragma("unroll")                                                         \
    for (int r = 0; r < 4; ++r)                                               \
      av[r] = *(const bf16x8*)&lsA[buf][fra + r * 16 * 32];                   \
    _Pragma("unroll")                                                         \
    for (int c = 0; c < 4; ++c)                                               \
      bv[c] = *(const bf16x8*)&lsB[buf][frb + c * 16 * 32];                   \
    _Pragma("unroll")                                                         \
    for (int r = 0; r < 4; ++r)                                               \
      _Pragma("unroll")                                                       \
      for (int c = 0; c < 4; ++c)                                             \
        acc[r][c] = __builtin_amdgcn_mfma_f32_16x16x32_bf16(av[r], bv[c],     \
                                                            acc[r][c], 0, 0, 0); \
  }

  // prologue: stage tile 0
  STAGE(0, 0);
  __syncthreads();
  int cur = 0;
  for (int kk = 32; kk < klen; kk += 32) {
    STAGE(cur ^ 1, kk);        // issue next-tile loads (hide under compute)
    COMPUTE(cur);
    __syncthreads();           // vmcnt(0) drain of prefetch + barrier
    cur ^= 1;
  }
  COMPUTE(cur);                // final tile (no prefetch)
#undef STAGE
#undef COMPUTE

  const int erow = m0 + wr * 64 + (lane >> 4) * 4;
  const int ecol = n0 + wc * 64 + (lane & 15);
#pragma unroll
  for (int r = 0; r < 4; ++r)
#pragma unroll
    for (int c = 0; c < 4; ++c) {
      if (OBF) {
        __bf16* p = (__bf16*)C + (size_t)(erow + r * 16) * ldc + (ecol + c * 16);
#pragma unroll
        for (int j = 0; j < 4; ++j) p[(size_t)j * ldc] = (__bf16)acc[r][c][j];
      } else {
        float* p = (float*)C + (size_t)bz * zstride +
                   (size_t)(erow + r * 16) * ldc + (ecol + c * 16);
#pragma unroll
        for (int j = 0; j < 4; ++j) p[(size_t)j * ldc] = acc[r][c][j];
      }
    }
}

// ---- grouped softmax: 1-wave blocks, owner-lane serial walks over LDS stage. ----
// (R13 structure — best measured.) vp bf16: stage converts bf16->f32 in LDS;
// walks and exp stay f32. Zero atomics, zero shuffles.
__global__ __launch_bounds__(64) void seg_softmax(const __bf16* __restrict__ vp,
                                                  const int* __restrict__ bounds,
                                                  const int* __restrict__ seg,
                                                  const float* __restrict__ q_sqrt,
                                                  __bf16* __restrict__ f) {
  __shared__ float sv[SVC];      // staged v (f32), overwritten with e by walks
  __shared__ float ssc[GQW];     // per-group scale q^2/den
  const int tid = threadIdx.x;
  const int b = blockIdx.x;
  const int g0 = blockIdx.y * GQW;

  const int s0 = bounds[g0];
  const int e0 = (blockIdx.y == NQW - 1) ? N_P : bounds[g0 + GQW];
  const int s0a = s0 & ~3;
  const int e0a = (e0 + 3) & ~3;
  const __bf16* row = vp + (size_t)b * N_PP;

  // stage slice: coalesced bf16x4 load, convert to f32
  for (int i = tid; i * 4 < e0a - s0a; i += 64) {
    bf16x4 v4 = *(const bf16x4*)&row[s0a + i * 4];
    f32x4 v;
#pragma unroll
    for (int j = 0; j < 4; ++j) v[j] = (float)v4[j];
    *(f32x4*)&sv[i * 4] = v;
  }
  __syncthreads();

  // owner-lane walks: 2 rounds of 64 groups
#pragma unroll
  for (int round = 0; round < 2; ++round) {
    int g = g0 + round * 64 + tid;
    if (g < g0 + GQW) {
      int s = bounds[g], e = bounds[g + 1];
      float m = -3.4e38f;
      for (int p = s; p < e; ++p) m = fmaxf(m, sv[p - s0a]);
      float den = 0.f;
      for (int p = s; p < e; ++p) {
        float t = __expf(sv[p - s0a] - m);
        den += t;
        sv[p - s0a] = t;
      }
      float qs = q_sqrt[g];
      ssc[g - g0] = (s < e) ? qs * qs / den : 0.f;
    }
  }
  __syncthreads();

  // vectorized sweep: scale + coalesced store (mask out-of-slice elems)
  __bf16* frow = f + (size_t)b * N_PP;
#pragma unroll
  for (int c = 0; c < NCH; ++c) {
    int p = s0a + (c * 64 + tid) * 4;
    if (p >= e0a) continue;
    f32x4 e4 = *(const f32x4*)&sv[p - s0a];
    i32x4 sgv = *(const i32x4*)&seg[p];
    bf16x4 o;
    bool ok[4];
#pragma unroll
    for (int j = 0; j < 4; ++j) {
      int gi = sgv[j] - g0;
      ok[j] = (unsigned)gi < (unsigned)GQW;
      int idx = ok[j] ? gi : 0;
      o[j] = (__bf16)(e4[j] * ssc[idx]);
    }
    if (ok[0] && ok[3]) {
      *(bf16x4*)&frow[p] = o;
    } else {
#pragma unroll
      for (int j = 0; j < 4; ++j)
        if (ok[j]) frow[p + j] = o[j];
    }
  }
  // zero padded tail so GEMM2's K-padding contributes nothing
  if (blockIdx.y == NQW - 1)
    for (int p = N_P + tid; p < N_PP; p += 64) frow[p] = (__bf16)0.f;
}

// ---- reduce split-K partials -> out (only l < 500) ----
__global__ __launch_bounds__(256) void reduce_out(const float* __restrict__ part,
                                                  float* __restrict__ out) {
  int idx = blockIdx.x * 256 + threadIdx.x;   // over 1536*500
  if (idx >= M_B * N_L) return;
  int b = idx / N_L, l = idx - b * N_L;
  float s = 0.f;
#pragma unroll
  for (int z = 0; z < SPLITK; ++z)
    s += part[(size_t)z * M_B * N_LP + (size_t)b * N_LP + l];
  out[idx] = s;
}

extern "C" void kernel_launch(void* const* d_in, const int* in_sizes, int n_in,
                              void* d_out, int out_size, void* d_ws, size_t ws_size,
                              hipStream_t stream) {
  const float* X           = (const float*)d_in[0];
  const float* theta       = (const float*)d_in[1];
  const float* theta_links = (const float*)d_in[2];
  const float* q_sqrt      = (const float*)d_in[3];
  const float* D           = (const float*)d_in[4];
  const int*   seg         = (const int*)d_in[5];
  float* out = (float*)d_out;

  char* ws = (char*)d_ws;
  __bf16* A1   = (__bf16*)(ws + OFF_A1);
  __bf16* D1   = (__bf16*)(ws + OFF_D1);
  __bf16* Dt   = (__bf16*)(ws + OFF_DT);
  __bf16* vp   = (__bf16*)(ws + OFF_VP);
  float*  part = (float*)(ws + OFF_PART);
  __bf16* fbuf = (__bf16*)(ws + OFF_F);
  int*    bnd  = (int*)(ws + OFF_BND);

  prep_a1<<<(M_B * N_LP) / 256, 256, 0, stream>>>(X, theta, theta_links, A1);
  prep_d<<<dim3(N_PP / 32, N_LP / 32), dim3(32, 8), 0, stream>>>(D, D1, Dt);
  seg_bounds<<<16, 256, 0, stream>>>(seg, bnd);

  // GEMM1 (XCD-chunked, bf16 out, 2-phase): vp[b][p] = sum_l A1[b][l] * Dt[p][l]
  gemm_bt<1, 1><<<dim3(NB1, 1, 1), 256, 0, stream>>>(
      A1, Dt, vp, N_LP, N_LP, N_PP, N_LP, N_LP, (size_t)0);

  // softmax: 1-wave owner-lane blocks, grid (1536 rows, 32 group-slices)
  seg_softmax<<<dim3(M_B, NQW), 64, 0, stream>>>(vp, bnd, seg, q_sqrt, fbuf);

  // GEMM2 (split-K, z-swizzled, 2-phase): part[z][b][l] = sum_{k in z} f[b][k]*D1[l][k]
  gemm_bt<2, 0><<<dim3((N_LP / 128) * (M_B / 128) * SPLITK, 1, 1), 256, 0, stream>>>(
      fbuf, D1, part, N_PP, N_PP, N_LP, N_PP, KCHUNK2, (size_t)(M_B * N_LP));

  reduce_out<<<(M_B * N_L + 255) / 256, 256, 0, stream>>>(part, out);
}

// Round 16
// 173.070 us; speedup vs baseline: 2.0423x; 1.0260x over previous
//
#include <hip/hip_runtime.h>
#include <hip/hip_bf16.h>
#include <stdint.h>

// Problem constants
#define M_B   1536      // 64*24 batch rows
#define N_L   500       // links
#define N_LP  512       // padded links (K of GEMM1, N of GEMM2)
#define N_P   20000     // paths
#define N_PP  20096     // padded paths (N of GEMM1 = 157*128, K of GEMM2)
#define N_G   4000      // OD groups
#define SPLITK 16
#define KCHUNK2 1280    // split-K chunk for GEMM2 (last = 896; both %32==0)
#define NQW   32        // row split for softmax (1-wave blocks)
#define GQW   (N_G / NQW)  // 125 groups per block
#define SVC   1024      // LDS staged floats per block (slice ~625, sigma~25 -> +16 sigma)
#define GUNR  12        // unrolled group-walk length; Poisson(5): P(size>12)~0.2% -> rare tail
#define NT1   (N_PP / 128)  // 157 n-tiles in GEMM1
#define MT1   (M_B / 128)   // 12 m-tiles
#define NB1   (NT1 * MT1)   // 1884 blocks

// Workspace layout (bytes). part aliases vp (vp dead after softmax).
#define OFF_A1   ((size_t)0)                    // bf16 [1536][512]      1,572,864
#define OFF_D1   ((size_t)1572864)              // bf16 [512][20096]    20,578,304
#define OFF_DT   ((size_t)22151168)             // bf16 [20096][512]    20,578,304
#define OFF_VP   ((size_t)42729472)             // bf16 [1536][20096]   61,734,912
#define OFF_PART OFF_VP                         // f32  [16][1536][512] 50,331,648 (aliases vp)
#define OFF_F    ((size_t)166199296)            // bf16 [1536][20096]   61,734,912
#define OFF_BND  ((size_t)227934208)            // int  [4001]

typedef __bf16 bf16x8 __attribute__((ext_vector_type(8)));
typedef __bf16 bf16x4 __attribute__((ext_vector_type(4)));
typedef float  f32x4  __attribute__((ext_vector_type(4)));
typedef int    i32x4  __attribute__((ext_vector_type(4)));

__device__ __forceinline__ void gload16(const void* g, void* l) {
  __builtin_amdgcn_global_load_lds(
      (const __attribute__((address_space(1))) void*)g,
      (__attribute__((address_space(3))) void*)l, 16, 0, 0);
}

// ---- prep: v_links -> bf16 A1 [1536][512], zero-padded ----
__global__ __launch_bounds__(256) void prep_a1(const float* __restrict__ X,
                                               const float* __restrict__ theta,
                                               const float* __restrict__ theta_links,
                                               __bf16* __restrict__ A1) {
  int idx = blockIdx.x * 256 + threadIdx.x;           // over 1536*512
  if (idx >= M_B * N_LP) return;
  int b = idx >> 9, l = idx & (N_LP - 1);
  float v = 0.f;
  if (l < N_L) {
    const float* x = X + ((size_t)b * N_L + l) * 5;
#pragma unroll
    for (int f = 0; f < 5; ++f) v += x[f] * fminf(theta[f], 0.f);
    v += theta_links[l];
  }
  A1[idx] = (__bf16)v;
}

// ---- prep: D -> bf16 D1 [512][20096] (row copy) AND Dt [20096][512] (transpose) ----
__global__ __launch_bounds__(256) void prep_d(const float* __restrict__ D,
                                              __bf16* __restrict__ D1,
                                              __bf16* __restrict__ Dt) {
  __shared__ float t[32][33];
  int pb = blockIdx.x * 32;   // path block
  int lb = blockIdx.y * 32;   // link block
  for (int i = threadIdx.y; i < 32; i += 8) {
    int l = lb + i, p = pb + threadIdx.x;
    float v = (l < N_L && p < N_P) ? D[(size_t)l * N_P + p] : 0.f;
    t[i][threadIdx.x] = v;
    D1[(size_t)l * N_PP + p] = (__bf16)v;
  }
  __syncthreads();
  for (int i = threadIdx.y; i < 32; i += 8) {
    int p = pb + i, l = lb + threadIdx.x;
    Dt[(size_t)p * N_LP + l] = (__bf16)t[threadIdx.x][i];
  }
}

// ---- segment bounds: bounds[g] = first path index with seg >= g ----
__global__ __launch_bounds__(256) void seg_bounds(const int* __restrict__ seg,
                                                  int* __restrict__ bounds) {
  int g = blockIdx.x * 256 + threadIdx.x;
  if (g > N_G) return;
  int lo = 0, hi = N_P;
  while (lo < hi) { int mid = (lo + hi) >> 1; if (seg[mid] < g) lo = mid + 1; else hi = mid; }
  bounds[g] = lo;
}

// ---- GEMM (A and Bt row-major over K): C[m][n] = sum_k A[m][k]*Bt[n][k] ----
// 128x128 tile, 4 waves (2x2), BK=32, 2-phase double-buffered prefetch (R15).
// MODE=1 (GEMM1): bijective XCD-chunked n-major map (Dt tiles L2-resident/XCD).
// MODE=2 (GEMM2): z-major z=bid&15 (D1 slices L2-resident/XCD).
// OBF=1: store C as bf16 (halves vp write traffic).
template <int MODE, int OBF>
__global__ __launch_bounds__(256) void gemm_bt(const __bf16* __restrict__ A,
                                               const __bf16* __restrict__ Bt,
                                               void* __restrict__ C,
                                               int lda, int ldb, int ldc,
                                               int K, int kchunk, size_t zstride) {
  int bx, by, bz;
  if (MODE == 1) {
    int x = blockIdx.x & 7, k = blockIdx.x >> 3;
    int start = (x < 4) ? 236 * x : 944 + 235 * (x - 4);
    int L = start + k;
    bx = L / MT1;  by = L - bx * MT1;  bz = 0;
  } else {
    int bid = blockIdx.x; bz = bid & 15; bx = (bid >> 4) & 3; by = bid >> 6;
  }
  __shared__ __bf16 lsA[2][128 * 32];
  __shared__ __bf16 lsB[2][128 * 32];
  const int tid = threadIdx.x;
  const int lane = tid & 63;
  const int wv = tid >> 6;
  const int wr = wv >> 1, wc = wv & 1;
  const int m0 = by * 128;
  const int n0 = bx * 128;
  const int kb = bz * kchunk;
  const int klen = min(kchunk, K - kb);

  const int srow = wv * 16 + (lane >> 2);
  const int scol = (lane & 3) * 8;
  const int sb = (wv * 16) * 32;            // wave's staging base within a buffer
  const __bf16* gA = A + (size_t)(m0 + srow) * lda + kb + scol;
  const __bf16* gB = Bt + (size_t)(n0 + srow) * ldb + kb + scol;

  f32x4 acc[4][4] = {};
  const int fra = (wr * 64 + (lane & 15)) * 32 + 8 * (lane >> 4);
  const int frb = (wc * 64 + (lane & 15)) * 32 + 8 * (lane >> 4);

#define STAGE(buf, kk)                                                        \
  {                                                                           \
    gload16(gA + (kk), &lsA[buf][sb]);                                        \
    gload16(gA + (size_t)64 * lda + (kk), &lsA[buf][64 * 32 + sb]);           \
    gload16(gB + (kk), &lsB[buf][sb]);                                        \
    gload16(gB + (size_t)64 * ldb + (kk), &lsB[buf][64 * 32 + sb]);           \
  }
#define COMPUTE(buf)                                                          \
  {                                                                           \
    bf16x8 av[4], bv[4];                                                      \
    _Pragma("unroll")                                                         \
    for (int r = 0; r < 4; ++r)                                               \
      av[r] = *(const bf16x8*)&lsA[buf][fra + r * 16 * 32];                   \
    _Pragma("unroll")                                                         \
    for (int c = 0; c < 4; ++c)                                               \
      bv[c] = *(const bf16x8*)&lsB[buf][frb + c * 16 * 32];                   \
    _Pragma("unroll")                                                         \
    for (int r = 0; r < 4; ++r)                                               \
      _Pragma("unroll")                                                       \
      for (int c = 0; c < 4; ++c)                                             \
        acc[r][c] = __builtin_amdgcn_mfma_f32_16x16x32_bf16(av[r], bv[c],     \
                                                            acc[r][c], 0, 0, 0); \
  }

  STAGE(0, 0);
  __syncthreads();
  int cur = 0;
  for (int kk = 32; kk < klen; kk += 32) {
    STAGE(cur ^ 1, kk);        // issue next-tile loads (hide under compute)
    COMPUTE(cur);
    __syncthreads();           // vmcnt(0) drain of prefetch + barrier
    cur ^= 1;
  }
  COMPUTE(cur);                // final tile (no prefetch)
#undef STAGE
#undef COMPUTE

  const int erow = m0 + wr * 64 + (lane >> 4) * 4;
  const int ecol = n0 + wc * 64 + (lane & 15);
#pragma unroll
  for (int r = 0; r < 4; ++r)
#pragma unroll
    for (int c = 0; c < 4; ++c) {
      if (OBF) {
        __bf16* p = (__bf16*)C + (size_t)(erow + r * 16) * ldc + (ecol + c * 16);
#pragma unroll
        for (int j = 0; j < 4; ++j) p[(size_t)j * ldc] = (__bf16)acc[r][c][j];
      } else {
        float* p = (float*)C + (size_t)bz * zstride +
                   (size_t)(erow + r * 16) * ldc + (ecol + c * 16);
#pragma unroll
        for (int j = 0; j < 4; ++j) p[(size_t)j * ldc] = acc[r][c][j];
      }
    }
}

// ---- grouped softmax: 1-wave blocks, REGISTERIZED owner-lane groups. ----
// R15 was VALU-issue-bound (76% busy): 3 divergent runtime-trip walks + masked
// sweep + seg loads = ~4 LDS touches/elem. Here: stage slice in LDS once; each
// owner lane pulls its group's <=GUNR elems into registers via statically-
// unrolled clamped ds_reads, then max/exp/store fully in regs (1 exp/elem,
// ev[] reused for the store). Direct owner-contiguous bf16 stores to f — the
// path-parallel sweep, seg reads, ssc table, and masking are deleted. Rare
// groups >GUNR take a divergent tail loop (P~0.2%).
__global__ __launch_bounds__(64) void seg_softmax(const __bf16* __restrict__ vp,
                                                  const int* __restrict__ bounds,
                                                  const float* __restrict__ q_sqrt,
                                                  __bf16* __restrict__ f) {
  __shared__ float sv[SVC];      // staged v (f32)
  const int tid = threadIdx.x;
  const int b = blockIdx.x;
  const int g0 = blockIdx.y * GQW;

  const int s0 = bounds[g0];
  const int e0 = (blockIdx.y == NQW - 1) ? N_P : bounds[g0 + GQW];
  const int s0a = s0 & ~3;
  const int e0a = (e0 + 3) & ~3;
  const __bf16* row = vp + (size_t)b * N_PP;

  // stage slice: coalesced bf16x4 load, convert to f32
  for (int i = tid; i * 4 < e0a - s0a; i += 64) {
    bf16x4 v4 = *(const bf16x4*)&row[s0a + i * 4];
    f32x4 v;
#pragma unroll
    for (int j = 0; j < 4; ++j) v[j] = (float)v4[j];
    *(f32x4*)&sv[i * 4] = v;
  }
  __syncthreads();

  __bf16* frow = f + (size_t)b * N_PP;

  // owner-lane groups: 2 rounds of 64
#pragma unroll
  for (int round = 0; round < 2; ++round) {
    int g = g0 + round * 64 + tid;
    if (g < g0 + GQW) {
      int s = bounds[g], e = bounds[g + 1];
      if (s < e) {
        // pull <=GUNR elems into registers (clamped, statically indexed)
        float v[GUNR];
#pragma unroll
        for (int j = 0; j < GUNR; ++j) {
          int p = s + j;
          v[j] = sv[(p < e ? p : e - 1) - s0a];
        }
        // max
        float m = v[0];
#pragma unroll
        for (int j = 1; j < GUNR; ++j)
          if (s + j < e) m = fmaxf(m, v[j]);
        for (int p = s + GUNR; p < e; ++p) m = fmaxf(m, sv[p - s0a]);  // rare tail
        // exp + denom (ev kept for store)
        float ev[GUNR];
        float den = 0.f;
#pragma unroll
        for (int j = 0; j < GUNR; ++j) {
          float t = __expf(v[j] - m);
          t = (s + j < e) ? t : 0.f;
          ev[j] = t;
          den += t;
        }
        for (int p = s + GUNR; p < e; ++p) den += __expf(sv[p - s0a] - m);
        float qs = q_sqrt[g];
        float sc = qs * qs / den;
        // store
#pragma unroll
        for (int j = 0; j < GUNR; ++j)
          if (s + j < e) frow[s + j] = (__bf16)(ev[j] * sc);
        for (int p = s + GUNR; p < e; ++p)
          frow[p] = (__bf16)(__expf(sv[p - s0a] - m) * sc);
      }
    }
  }
  // zero padded tail so GEMM2's K-padding contributes nothing
  if (blockIdx.y == NQW - 1)
    for (int p = N_P + tid; p < N_PP; p += 64) frow[p] = (__bf16)0.f;
}

// ---- reduce split-K partials -> out (only l < 500) ----
__global__ __launch_bounds__(256) void reduce_out(const float* __restrict__ part,
                                                  float* __restrict__ out) {
  int idx = blockIdx.x * 256 + threadIdx.x;   // over 1536*500
  if (idx >= M_B * N_L) return;
  int b = idx / N_L, l = idx - b * N_L;
  float s = 0.f;
#pragma unroll
  for (int z = 0; z < SPLITK; ++z)
    s += part[(size_t)z * M_B * N_LP + (size_t)b * N_LP + l];
  out[idx] = s;
}

extern "C" void kernel_launch(void* const* d_in, const int* in_sizes, int n_in,
                              void* d_out, int out_size, void* d_ws, size_t ws_size,
                              hipStream_t stream) {
  const float* X           = (const float*)d_in[0];
  const float* theta       = (const float*)d_in[1];
  const float* theta_links = (const float*)d_in[2];
  const float* q_sqrt      = (const float*)d_in[3];
  const float* D           = (const float*)d_in[4];
  const int*   seg         = (const int*)d_in[5];
  float* out = (float*)d_out;

  char* ws = (char*)d_ws;
  __bf16* A1   = (__bf16*)(ws + OFF_A1);
  __bf16* D1   = (__bf16*)(ws + OFF_D1);
  __bf16* Dt   = (__bf16*)(ws + OFF_DT);
  __bf16* vp   = (__bf16*)(ws + OFF_VP);
  float*  part = (float*)(ws + OFF_PART);
  __bf16* fbuf = (__bf16*)(ws + OFF_F);
  int*    bnd  = (int*)(ws + OFF_BND);

  prep_a1<<<(M_B * N_LP) / 256, 256, 0, stream>>>(X, theta, theta_links, A1);
  prep_d<<<dim3(N_PP / 32, N_LP / 32), dim3(32, 8), 0, stream>>>(D, D1, Dt);
  seg_bounds<<<16, 256, 0, stream>>>(seg, bnd);

  // GEMM1 (XCD-chunked, bf16 out, 2-phase): vp[b][p] = sum_l A1[b][l] * Dt[p][l]
  gemm_bt<1, 1><<<dim3(NB1, 1, 1), 256, 0, stream>>>(
      A1, Dt, vp, N_LP, N_LP, N_PP, N_LP, N_LP, (size_t)0);

  // softmax: 1-wave registerized owner-lane blocks, grid (1536 rows, 32 slices)
  seg_softmax<<<dim3(M_B, NQW), 64, 0, stream>>>(vp, bnd, q_sqrt, fbuf);

  // GEMM2 (split-K, z-swizzled, 2-phase): part[z][b][l] = sum_{k in z} f[b][k]*D1[l][k]
  gemm_bt<2, 0><<<dim3((N_LP / 128) * (M_B / 128) * SPLITK, 1, 1), 256, 0, stream>>>(
      fbuf, D1, part, N_PP, N_PP, N_LP, N_PP, KCHUNK2, (size_t)(M_B * N_LP));

  reduce_out<<<(M_B * N_L + 255) / 256, 256, 0, stream>>>(part, out);
}

// Round 17
// 166.668 us; speedup vs baseline: 2.1207x; 1.0384x over previous
//
#include <hip/hip_runtime.h>
#include <hip/hip_bf16.h>
#include <stdint.h>

// Problem constants
#define M_B   1536      // 64*24 batch rows
#define N_L   500       // links
#define N_LP  512       // padded links (K of GEMM1, N of GEMM2)
#define N_P   20000     // paths
#define N_PP  20096     // padded paths (N of GEMM1 = 157*128, K of GEMM2)
#define N_G   4000      // OD groups
#define SPLITK 16
#define KCHUNK2 1280    // split-K chunk for GEMM2 (last = 896; both %32==0)
#define NQW   32        // row split for softmax (1-wave blocks)
#define GQW   (N_G / NQW)  // 125 groups per block
#define SVB   1024      // LDS staged bf16 per block (slice ~625+align, sigma~25 -> +15 sigma)
#define GUNR  12        // unrolled group-walk length; P(size>12)~0.2% -> rare tail
#define NT1   (N_PP / 128)  // 157 n-tiles in GEMM1
#define MT1   (M_B / 128)   // 12 m-tiles
#define NB1   (NT1 * MT1)   // 1884 blocks

// Workspace layout (bytes). part (bf16, 25 MB) aliases vp (vp dead after softmax).
#define OFF_A1   ((size_t)0)                    // bf16 [1536][512]      1,572,864
#define OFF_D1   ((size_t)1572864)              // bf16 [512][20096]    20,578,304
#define OFF_DT   ((size_t)22151168)             // bf16 [20096][512]    20,578,304
#define OFF_VP   ((size_t)42729472)             // bf16 [1536][20096]   61,734,912
#define OFF_PART OFF_VP                         // bf16 [16][1536][512] 25,165,824 (aliases vp)
#define OFF_F    ((size_t)166199296)            // bf16 [1536][20096]   61,734,912
#define OFF_BND  ((size_t)227934208)            // int  [4001]

typedef __bf16 bf16x8 __attribute__((ext_vector_type(8)));
typedef __bf16 bf16x4 __attribute__((ext_vector_type(4)));
typedef float  f32x4  __attribute__((ext_vector_type(4)));
typedef int    i32x4  __attribute__((ext_vector_type(4)));

__device__ __forceinline__ void gload16(const void* g, void* l) {
  __builtin_amdgcn_global_load_lds(
      (const __attribute__((address_space(1))) void*)g,
      (__attribute__((address_space(3))) void*)l, 16, 0, 0);
}

// ---- prep: v_links -> bf16 A1 [1536][512], zero-padded ----
__global__ __launch_bounds__(256) void prep_a1(const float* __restrict__ X,
                                               const float* __restrict__ theta,
                                               const float* __restrict__ theta_links,
                                               __bf16* __restrict__ A1) {
  int idx = blockIdx.x * 256 + threadIdx.x;           // over 1536*512
  if (idx >= M_B * N_LP) return;
  int b = idx >> 9, l = idx & (N_LP - 1);
  float v = 0.f;
  if (l < N_L) {
    const float* x = X + ((size_t)b * N_L + l) * 5;
#pragma unroll
    for (int f = 0; f < 5; ++f) v += x[f] * fminf(theta[f], 0.f);
    v += theta_links[l];
  }
  A1[idx] = (__bf16)v;
}

// ---- prep: D -> bf16 D1 [512][20096] (row copy) AND Dt [20096][512] (transpose) ----
__global__ __launch_bounds__(256) void prep_d(const float* __restrict__ D,
                                              __bf16* __restrict__ D1,
                                              __bf16* __restrict__ Dt) {
  __shared__ float t[32][33];
  int pb = blockIdx.x * 32;   // path block
  int lb = blockIdx.y * 32;   // link block
  for (int i = threadIdx.y; i < 32; i += 8) {
    int l = lb + i, p = pb + threadIdx.x;
    float v = (l < N_L && p < N_P) ? D[(size_t)l * N_P + p] : 0.f;
    t[i][threadIdx.x] = v;
    D1[(size_t)l * N_PP + p] = (__bf16)v;
  }
  __syncthreads();
  for (int i = threadIdx.y; i < 32; i += 8) {
    int p = pb + i, l = lb + threadIdx.x;
    Dt[(size_t)p * N_LP + l] = (__bf16)t[threadIdx.x][i];
  }
}

// ---- segment bounds: bounds[g] = first path index with seg >= g ----
__global__ __launch_bounds__(256) void seg_bounds(const int* __restrict__ seg,
                                                  int* __restrict__ bounds) {
  int g = blockIdx.x * 256 + threadIdx.x;
  if (g > N_G) return;
  int lo = 0, hi = N_P;
  while (lo < hi) { int mid = (lo + hi) >> 1; if (seg[mid] < g) lo = mid + 1; else hi = mid; }
  bounds[g] = lo;
}

// ---- GEMM (A and Bt row-major over K): C[m][n] = sum_k A[m][k]*Bt[n][k] ----
// 128x128 tile, 4 waves (2x2), BK=32, 2-phase double-buffered prefetch (R15).
// MODE=1 (GEMM1): bijective XCD-chunked n-major map (Dt tiles L2-resident/XCD).
// MODE=2 (GEMM2): z-major z=bid&15 (D1 slices L2-resident/XCD).
// OBF=1: store C as bf16 (halves write traffic; zstride in elems).
template <int MODE, int OBF>
__global__ __launch_bounds__(256) void gemm_bt(const __bf16* __restrict__ A,
                                               const __bf16* __restrict__ Bt,
                                               void* __restrict__ C,
                                               int lda, int ldb, int ldc,
                                               int K, int kchunk, size_t zstride) {
  int bx, by, bz;
  if (MODE == 1) {
    int x = blockIdx.x & 7, k = blockIdx.x >> 3;
    int start = (x < 4) ? 236 * x : 944 + 235 * (x - 4);
    int L = start + k;
    bx = L / MT1;  by = L - bx * MT1;  bz = 0;
  } else {
    int bid = blockIdx.x; bz = bid & 15; bx = (bid >> 4) & 3; by = bid >> 6;
  }
  __shared__ __bf16 lsA[2][128 * 32];
  __shared__ __bf16 lsB[2][128 * 32];
  const int tid = threadIdx.x;
  const int lane = tid & 63;
  const int wv = tid >> 6;
  const int wr = wv >> 1, wc = wv & 1;
  const int m0 = by * 128;
  const int n0 = bx * 128;
  const int kb = bz * kchunk;
  const int klen = min(kchunk, K - kb);

  const int srow = wv * 16 + (lane >> 2);
  const int scol = (lane & 3) * 8;
  const int sb = (wv * 16) * 32;            // wave's staging base within a buffer
  const __bf16* gA = A + (size_t)(m0 + srow) * lda + kb + scol;
  const __bf16* gB = Bt + (size_t)(n0 + srow) * ldb + kb + scol;

  f32x4 acc[4][4] = {};
  const int fra = (wr * 64 + (lane & 15)) * 32 + 8 * (lane >> 4);
  const int frb = (wc * 64 + (lane & 15)) * 32 + 8 * (lane >> 4);

#define STAGE(buf, kk)                                                        \
  {                                                                           \
    gload16(gA + (kk), &lsA[buf][sb]);                                        \
    gload16(gA + (size_t)64 * lda + (kk), &lsA[buf][64 * 32 + sb]);           \
    gload16(gB + (kk), &lsB[buf][sb]);                                        \
    gload16(gB + (size_t)64 * ldb + (kk), &lsB[buf][64 * 32 + sb]);           \
  }
#define COMPUTE(buf)                                                          \
  {                                                                           \
    bf16x8 av[4], bv[4];                                                      \
    _Pragma("unroll")                                                         \
    for (int r = 0; r < 4; ++r)                                               \
      av[r] = *(const bf16x8*)&lsA[buf][fra + r * 16 * 32];                   \
    _Pragma("unroll")                                                         \
    for (int c = 0; c < 4; ++c)                                               \
      bv[c] = *(const bf16x8*)&lsB[buf][frb + c * 16 * 32];                   \
    _Pragma("unroll")                                                         \
    for (int r = 0; r < 4; ++r)                                               \
      _Pragma("unroll")                                                       \
      for (int c = 0; c < 4; ++c)                                             \
        acc[r][c] = __builtin_amdgcn_mfma_f32_16x16x32_bf16(av[r], bv[c],     \
                                                            acc[r][c], 0, 0, 0); \
  }

  STAGE(0, 0);
  __syncthreads();
  int cur = 0;
  for (int kk = 32; kk < klen; kk += 32) {
    STAGE(cur ^ 1, kk);        // issue next-tile loads (hide under compute)
    COMPUTE(cur);
    __syncthreads();           // vmcnt(0) drain of prefetch + barrier
    cur ^= 1;
  }
  COMPUTE(cur);                // final tile (no prefetch)
#undef STAGE
#undef COMPUTE

  const int erow = m0 + wr * 64 + (lane >> 4) * 4;
  const int ecol = n0 + wc * 64 + (lane & 15);
#pragma unroll
  for (int r = 0; r < 4; ++r)
#pragma unroll
    for (int c = 0; c < 4; ++c) {
      if (OBF) {
        __bf16* p = (__bf16*)C + (size_t)bz * zstride +
                    (size_t)(erow + r * 16) * ldc + (ecol + c * 16);
#pragma unroll
        for (int j = 0; j < 4; ++j) p[(size_t)j * ldc] = (__bf16)acc[r][c][j];
      } else {
        float* p = (float*)C + (size_t)bz * zstride +
                   (size_t)(erow + r * 16) * ldc + (ecol + c * 16);
#pragma unroll
        for (int j = 0; j < 4; ++j) p[(size_t)j * ldc] = acc[r][c][j];
      }
    }
}

// ---- grouped softmax: 1-wave blocks, registerized owner-lane groups,
//      stage via global_load_lds of RAW bf16 (async, no VGPR round-trip). ----
// R16 analysis: stage convert pass ~80 instr/block + exp (~25us chip-wide,
// irreducible) dominated. Stage is now 2 gload16 calls; conversion happens in
// the 12 clamped reads that already exist. Max over clamped duplicates is safe
// (duplicate of a real element); duplicates are zeroed for the denom.
__global__ __launch_bounds__(64) void seg_softmax(const __bf16* __restrict__ vp,
                                                  const int* __restrict__ bounds,
                                                  const float* __restrict__ q_sqrt,
                                                  __bf16* __restrict__ f) {
  __shared__ __bf16 svb[SVB];    // staged raw bf16 slice
  const int tid = threadIdx.x;
  const int b = blockIdx.x;
  const int g0 = blockIdx.y * GQW;

  const int s0 = bounds[g0];
  const int e0 = (blockIdx.y == NQW - 1) ? N_P : bounds[g0 + GQW];
  const int s0b = s0 & ~7;       // 16B-aligned element base
  const __bf16* row = vp + (size_t)b * N_PP;

  // async stage: 2 x (64 lanes x 16B) = 2048B = 1024 bf16 (covers slice ~632+)
  gload16(row + s0b + tid * 8, &svb[0]);
  gload16(row + s0b + 512 + tid * 8, &svb[512]);
  __syncthreads();               // vmcnt(0) + barrier

  __bf16* frow = f + (size_t)b * N_PP;

  // owner-lane groups: 2 rounds of 64
#pragma unroll
  for (int round = 0; round < 2; ++round) {
    int g = g0 + round * 64 + tid;
    if (g < g0 + GQW) {
      int s = bounds[g], e = bounds[g + 1];
      if (s < e) {
        // pull <=GUNR elems into registers (clamped, statically indexed)
        float v[GUNR];
#pragma unroll
        for (int j = 0; j < GUNR; ++j) {
          int p = s + j;
          v[j] = (float)svb[(p < e ? p : e - 1) - s0b];
        }
        // max (clamped duplicates can't change it)
        float m = v[0];
#pragma unroll
        for (int j = 1; j < GUNR; ++j) m = fmaxf(m, v[j]);
        for (int p = s + GUNR; p < e; ++p) m = fmaxf(m, (float)svb[p - s0b]);
        // exp + denom (ev kept in regs for the store)
        float ev[GUNR];
        float den = 0.f;
#pragma unroll
        for (int j = 0; j < GUNR; ++j) {
          float t = __expf(v[j] - m);
          t = (s + j < e) ? t : 0.f;
          ev[j] = t;
          den += t;
        }
        for (int p = s + GUNR; p < e; ++p) den += __expf((float)svb[p - s0b] - m);
        float qs = q_sqrt[g];
        float sc = qs * qs / den;
        // store
#pragma unroll
        for (int j = 0; j < GUNR; ++j)
          if (s + j < e) frow[s + j] = (__bf16)(ev[j] * sc);
        for (int p = s + GUNR; p < e; ++p)
          frow[p] = (__bf16)(__expf((float)svb[p - s0b] - m) * sc);
      }
    }
  }
  // zero padded tail so GEMM2's K-padding contributes nothing
  if (blockIdx.y == NQW - 1)
    for (int p = N_P + tid; p < N_PP; p += 64) frow[p] = (__bf16)0.f;
}

// ---- reduce split-K bf16 partials -> out (l < 500; 500 = 125*4) ----
__global__ __launch_bounds__(256) void reduce_out(const __bf16* __restrict__ part,
                                                  float* __restrict__ out) {
  int idx = blockIdx.x * 256 + threadIdx.x;   // over 1536*125
  if (idx >= M_B * 125) return;
  int b = idx / 125, l4 = (idx - b * 125) * 4;
  f32x4 s = {};
#pragma unroll
  for (int z = 0; z < SPLITK; ++z) {
    bf16x4 v = *(const bf16x4*)&part[(size_t)z * M_B * N_LP + (size_t)b * N_LP + l4];
#pragma unroll
    for (int j = 0; j < 4; ++j) s[j] += (float)v[j];
  }
  *(f32x4*)&out[(size_t)b * N_L + l4] = s;
}

extern "C" void kernel_launch(void* const* d_in, const int* in_sizes, int n_in,
                              void* d_out, int out_size, void* d_ws, size_t ws_size,
                              hipStream_t stream) {
  const float* X           = (const float*)d_in[0];
  const float* theta       = (const float*)d_in[1];
  const float* theta_links = (const float*)d_in[2];
  const float* q_sqrt      = (const float*)d_in[3];
  const float* D           = (const float*)d_in[4];
  const int*   seg         = (const int*)d_in[5];
  float* out = (float*)d_out;

  char* ws = (char*)d_ws;
  __bf16* A1   = (__bf16*)(ws + OFF_A1);
  __bf16* D1   = (__bf16*)(ws + OFF_D1);
  __bf16* Dt   = (__bf16*)(ws + OFF_DT);
  __bf16* vp   = (__bf16*)(ws + OFF_VP);
  __bf16* part = (__bf16*)(ws + OFF_PART);
  __bf16* fbuf = (__bf16*)(ws + OFF_F);
  int*    bnd  = (int*)(ws + OFF_BND);

  prep_a1<<<(M_B * N_LP) / 256, 256, 0, stream>>>(X, theta, theta_links, A1);
  prep_d<<<dim3(N_PP / 32, N_LP / 32), dim3(32, 8), 0, stream>>>(D, D1, Dt);
  seg_bounds<<<16, 256, 0, stream>>>(seg, bnd);

  // GEMM1 (XCD-chunked, bf16 out, 2-phase): vp[b][p] = sum_l A1[b][l] * Dt[p][l]
  gemm_bt<1, 1><<<dim3(NB1, 1, 1), 256, 0, stream>>>(
      A1, Dt, vp, N_LP, N_LP, N_PP, N_LP, N_LP, (size_t)0);

  // softmax: 1-wave registerized owner-lane blocks, gload_lds stage
  seg_softmax<<<dim3(M_B, NQW), 64, 0, stream>>>(vp, bnd, q_sqrt, fbuf);

  // GEMM2 (split-K, z-swizzled, 2-phase, bf16 partials):
  // part[z][b][l] = sum_{k in z} f[b][k]*D1[l][k]
  gemm_bt<2, 1><<<dim3((N_LP / 128) * (M_B / 128) * SPLITK, 1, 1), 256, 0, stream>>>(
      fbuf, D1, part, N_PP, N_PP, N_LP, N_PP, KCHUNK2, (size_t)(M_B * N_LP));

  reduce_out<<<(M_B * 125 + 255) / 256, 256, 0, stream>>>(part, out);
}